// Round 2
// baseline (420.577 us; speedup 1.0000x reference)
//
#include <hip/hip_runtime.h>
#include <hip/hip_bf16.h>

#define DEVI __device__ __forceinline__

typedef __attribute__((ext_vector_type(8))) short short8;
typedef __attribute__((ext_vector_type(4))) short short4v;
typedef __attribute__((ext_vector_type(4))) float floatx4;

static constexpr int B_ = 2, T_ = 2048, C_ = 1024, H_ = 16, D_ = 64;

DEVI float bf2f(unsigned short u) {
    union { unsigned int i; float f; } v; v.i = ((unsigned int)u) << 16; return v.f;
}
DEVI unsigned short f2bf(float f) {
    union { float f; unsigned int i; } v; v.f = f;
    unsigned int x = v.i;
    return (unsigned short)((x + 0x7fffu + ((x >> 16) & 1u)) >> 16);
}

// async global->LDS, 16B per lane. LDS dest must be wave_base + lane*16.
DEVI void async16(const unsigned short* g, unsigned short* l) {
    __builtin_amdgcn_global_load_lds((const __attribute__((address_space(1))) void*)g,
                                     (__attribute__((address_space(3))) void*)l, 16, 0, 0);
}

// ---------------- convert fp32 -> bf16, 8 elems/thread ----------------
__global__ __launch_bounds__(256) void k_cvt(const float* __restrict__ in,
                                             unsigned short* __restrict__ out, int n8) {
    int i = blockIdx.x * 256 + threadIdx.x;
    if (i >= n8) return;
    const float4* p = (const float4*)in + (size_t)i * 2;
    float4 a = p[0], b = p[1];
    union { unsigned short u[8]; short8 s; } r;
    r.u[0] = f2bf(a.x); r.u[1] = f2bf(a.y); r.u[2] = f2bf(a.z); r.u[3] = f2bf(a.w);
    r.u[4] = f2bf(b.x); r.u[5] = f2bf(b.y); r.u[6] = f2bf(b.z); r.u[7] = f2bf(b.w);
    *(short8*)&out[(size_t)i * 8] = r.s;
}

// ---------------- transpose+convert: in f32 (K x N) -> out bf16 (N x K) ----------------
__global__ __launch_bounds__(256) void k_tr(const float* __restrict__ in,
                                            unsigned short* __restrict__ out, int K, int N) {
    __shared__ float tile[64][65];
    int k0 = blockIdx.y * 64, n0 = blockIdx.x * 64;
    int tid = threadIdx.x;
#pragma unroll
    for (int r = 0; r < 4; r++) {
        int ci = tid + r * 256;
        int row = ci >> 4, c4 = (ci & 15) * 4;
        float4 v = *(const float4*)&in[(size_t)(k0 + row) * N + n0 + c4];
        tile[row][c4 + 0] = v.x; tile[row][c4 + 1] = v.y;
        tile[row][c4 + 2] = v.z; tile[row][c4 + 3] = v.w;
    }
    __syncthreads();
#pragma unroll
    for (int r = 0; r < 2; r++) {
        int ci = tid + r * 256;
        int row = ci >> 3, c8 = (ci & 7) * 8;
        union { unsigned short u[8]; short8 s; } o;
#pragma unroll
        for (int j = 0; j < 8; j++) o.u[j] = f2bf(tile[c8 + j][row]);
        *(short8*)&out[(size_t)(n0 + row) * K + k0 + c8] = o.s;
    }
}

// ---------------- discourse bias: (d_bias - mean) * w_disc ----------------
__global__ __launch_bounds__(256) void k_bias(const float* __restrict__ d_bias,
                                              const float* __restrict__ w_disc,
                                              float* __restrict__ bias) {
    int h = blockIdx.x, tid = threadIdx.x;
    __shared__ float red[256];
    float s = 0.f;
    for (int t = tid; t < T_; t += 256) s += d_bias[h * T_ + t];
    red[tid] = s;
    __syncthreads();
    for (int st = 128; st > 0; st >>= 1) {
        if (tid < st) red[tid] += red[tid + st];
        __syncthreads();
    }
    float mean = red[0] * (1.0f / T_);
    float wd = w_disc[h];
    for (int t = tid; t < T_; t += 256) bias[h * T_ + t] = (d_bias[h * T_ + t] - mean) * wd;
}

// ---------------- bf16 GEMM: C(MxN) = A(MxK) * Bt(NxK)^T ----------------
template <typename OUT>
__global__ __launch_bounds__(256) void k_gemm(const unsigned short* __restrict__ A,
                                              const unsigned short* __restrict__ Bt,
                                              OUT* __restrict__ C, int M, int N, int K) {
    __shared__ __align__(16) unsigned short As[128 * 32];
    __shared__ __align__(16) unsigned short Bs[128 * 32];
    int m0 = blockIdx.y * 128, n0 = blockIdx.x * 128;
    int tid = threadIdx.x, l = tid & 63, w = tid >> 6;
    int wm = (w >> 1) * 64, wn = (w & 1) * 64;
    int lm = l & 15, lq = l >> 4;
    floatx4 acc[4][4];
#pragma unroll
    for (int a = 0; a < 4; a++)
#pragma unroll
        for (int b = 0; b < 4; b++) acc[a][b] = {0.f, 0.f, 0.f, 0.f};

    for (int k0 = 0; k0 < K; k0 += 32) {
        __syncthreads();
#pragma unroll
        for (int r = 0; r < 2; r++) {
            int ci = tid + r * 256;
            int row = ci >> 2, off = (ci & 3) * 8;
            async16(&A[(size_t)(m0 + row) * K + k0 + off], &As[row * 32 + off]);
            async16(&Bt[(size_t)(n0 + row) * K + k0 + off], &Bs[row * 32 + off]);
        }
        __syncthreads();
        short8 af[4], bf[4];
#pragma unroll
        for (int t = 0; t < 4; t++) af[t] = *(short8*)&As[(wm + t * 16 + lm) * 32 + lq * 8];
#pragma unroll
        for (int t = 0; t < 4; t++) bf[t] = *(short8*)&Bs[(wn + t * 16 + lm) * 32 + lq * 8];
#pragma unroll
        for (int tm = 0; tm < 4; tm++)
#pragma unroll
            for (int tn = 0; tn < 4; tn++)
                acc[tm][tn] = __builtin_amdgcn_mfma_f32_16x16x32_bf16(af[tm], bf[tn], acc[tm][tn], 0, 0, 0);
    }
#pragma unroll
    for (int tm = 0; tm < 4; tm++)
#pragma unroll
        for (int tn = 0; tn < 4; tn++) {
            int row = m0 + wm + tm * 16 + lq * 4;
            int col = n0 + wn + tn * 16 + lm;
#pragma unroll
            for (int r = 0; r < 4; r++) {
                float v = acc[tm][tn][r];
                if constexpr (sizeof(OUT) == 2) C[(size_t)(row + r) * N + col] = (OUT)f2bf(v);
                else                            C[(size_t)(row + r) * N + col] = v;
            }
        }
}

// ---------------- build q_eff (scaled by 1/8) and k_eff per head ----------------
__global__ __launch_bounds__(256) void k_build(const unsigned short* __restrict__ qkv,
                                               const float* __restrict__ W_recip,
                                               const float* __restrict__ w_std,
                                               const float* __restrict__ w_rec,
                                               unsigned short* __restrict__ qe,
                                               unsigned short* __restrict__ ke) {
    __shared__ float Wr[64 * 8];
    int tid = threadIdx.x;
    for (int i = tid; i < 512; i += 256) Wr[i] = W_recip[i];
    __syncthreads();
    int g = blockIdx.x * 256 + tid;       // over B*H*T
    int t = g & (T_ - 1), h = (g >> 11) & (H_ - 1), b = g >> 15;
    float ws = sqrtf(fmaxf(w_std[h], 1e-8f));
    float wr = sqrtf(fmaxf(w_rec[h], 1e-8f));
    bool ra = w_rec[h] > 0.1f;
    const unsigned short* qrow = qkv + (size_t)(b * T_ + t) * 3072 + h * 64;
    const unsigned short* krow = qrow + 1024;
    float q[64], k[64];
#pragma unroll
    for (int i = 0; i < 8; i++) {
        short8 qv = *(const short8*)&qrow[i * 8];
        short8 kv = *(const short8*)&krow[i * 8];
#pragma unroll
        for (int j = 0; j < 8; j++) {
            q[i * 8 + j] = bf2f((unsigned short)qv[j]);
            k[i * 8 + j] = bf2f((unsigned short)kv[j]);
        }
    }
    float QW[8], KW[8];
#pragma unroll
    for (int r = 0; r < 8; r++) { QW[r] = 0.f; KW[r] = 0.f; }
#pragma unroll
    for (int d = 0; d < 64; d++)
#pragma unroll
        for (int r = 0; r < 8; r++) {
            QW[r] += q[d] * Wr[d * 8 + r];
            KW[r] += k[d] * Wr[d * 8 + r];
        }
    size_t obase = (size_t)((b * H_ + h) * T_ + t) * 64;
#pragma unroll
    for (int i = 0; i < 8; i++) {
        union { unsigned short u[8]; short8 s; } uq, uk;
#pragma unroll
        for (int j = 0; j < 8; j++) {
            int d = i * 8 + j;
            float qv, kv;
            if (ra && d >= 56) { qv = wr * KW[d - 56]; kv = wr * QW[d - 56]; }  // q_aug<-KW, k_aug<-QW
            else               { qv = ws * q[d];       kv = ws * k[d]; }
            uq.u[j] = f2bf(qv * 0.125f);   // fold softmax scale (exact pow2) into q_eff
            uk.u[j] = f2bf(kv);
        }
        *(short8*)&qe[obase + i * 8] = uq.s;
        *(short8*)&ke[obase + i * 8] = uk.s;
    }
}

// ---------------- transpose V to (B,H,D,T) ----------------
__global__ __launch_bounds__(256) void k_vtr(const unsigned short* __restrict__ qkv,
                                             unsigned short* __restrict__ vt) {
    int tid = threadIdx.x;
    int g = blockIdx.x;                    // B*H*(T/32)
    int tchunk = g & 63;
    int h = (g >> 6) & 15, b = g >> 10;
    int d = tid & 63, tg = tid >> 6;
    int t0 = tchunk * 32 + tg * 8;
    union { unsigned short u[8]; short8 s; } v;
#pragma unroll
    for (int i = 0; i < 8; i++)
        v.u[i] = qkv[(size_t)(b * T_ + t0 + i) * 3072 + 2048 + h * 64 + d];
    *(short8*)&vt[(size_t)((b * H_ + h) * D_ + d) * T_ + t0] = v.s;
}

// ---------------- flash attention: wave-autonomous, no LDS, no barriers ----------------
// Each wave owns 16 q-rows. Computes S^T = K_eff Q_eff^T (i in lane dim), then
// O^T = V^T P^T so softmax state and output rows stay per-lane throughout.
__global__ __launch_bounds__(256) void k_attn(const unsigned short* __restrict__ qe,
                                              const unsigned short* __restrict__ ke,
                                              const unsigned short* __restrict__ vt,
                                              const float* __restrict__ bias,
                                              unsigned short* __restrict__ obf) {
    int bh = blockIdx.y;
    int b = bh >> 4, h = bh & 15;
    int tid = threadIdx.x, l = tid & 63, w = tid >> 6;
    int lm = l & 15, lq = l >> 4;
    int i0w = blockIdx.x * 64 + w * 16;     // this wave's q-row base
    int irow = i0w + lm;
    const size_t hb = (size_t)bh * T_ * 64;

    // Q B-frag (B[k][n=i]): lane lm = i, k = lq*8 + 0..7 (+32 for second half)
    const unsigned short* qrow = qe + hb + (size_t)irow * 64 + lq * 8;
    short8 qf0 = *(const short8*)qrow;
    short8 qf1 = *(const short8*)(qrow + 32);

    const unsigned short* keh = ke + hb;
    const unsigned short* vth = vt + hb;
    const float* biash = bias + h * T_;

    floatx4 Oacc[4];
#pragma unroll
    for (int i = 0; i < 4; i++) Oacc[i] = {0.f, 0.f, 0.f, 0.f};
    float m_i = -3e38f, l_i = 0.f;

    for (int j0 = 0; j0 < i0w + 16; j0 += 64) {
        // ---- S^T: 4 subtiles of 16 j-rows ----
        float sv[4][4];
#pragma unroll
        for (int js = 0; js < 4; js++) {
            const unsigned short* krow = keh + (size_t)(j0 + js * 16 + lm) * 64 + lq * 8;
            short8 kf0 = *(const short8*)krow;
            short8 kf1 = *(const short8*)(krow + 32);
            floatx4 s = {0.f, 0.f, 0.f, 0.f};
            s = __builtin_amdgcn_mfma_f32_16x16x32_bf16(kf0, qf0, s, 0, 0, 0);
            s = __builtin_amdgcn_mfma_f32_16x16x32_bf16(kf1, qf1, s, 0, 0, 0);
            int jb = j0 + js * 16 + lq * 4;
            float4 bj = *(const float4*)&biash[jb];
#pragma unroll
            for (int r = 0; r < 4; r++) {
                float bval = (r == 0) ? bj.x : (r == 1) ? bj.y : (r == 2) ? bj.z : bj.w;
                sv[js][r] = (jb + r <= irow) ? (s[r] + bval) : -1e9f;
            }
        }
        // ---- online softmax (row i = irow lives in this lane; quads hold j-subsets) ----
        float mx = sv[0][0];
#pragma unroll
        for (int js = 0; js < 4; js++)
#pragma unroll
            for (int r = 0; r < 4; r++) mx = fmaxf(mx, sv[js][r]);
        mx = fmaxf(mx, __shfl_xor(mx, 16));
        mx = fmaxf(mx, __shfl_xor(mx, 32));
        float mn = fmaxf(m_i, mx);
        float alpha = __expf(m_i - mn);
        m_i = mn;
        float rs = 0.f;
#pragma unroll
        for (int js = 0; js < 4; js++)
#pragma unroll
            for (int r = 0; r < 4; r++) {
                float p = __expf(sv[js][r] - mn);
                sv[js][r] = p;
                rs += p;
            }
        rs += __shfl_xor(rs, 16);
        rs += __shfl_xor(rs, 32);
        l_i = l_i * alpha + rs;
#pragma unroll
        for (int dt = 0; dt < 4; dt++) {
            floatx4 o = Oacc[dt];
            o[0] *= alpha; o[1] *= alpha; o[2] *= alpha; o[3] *= alpha;
            Oacc[dt] = o;
        }
        // ---- pack P (bf16 pairs): pk[js][0] = j(+0,+1), pk[js][1] = j(+2,+3) ----
        unsigned int pk[4][2];
#pragma unroll
        for (int js = 0; js < 4; js++) {
            pk[js][0] = (unsigned int)f2bf(sv[js][0]) | ((unsigned int)f2bf(sv[js][1]) << 16);
            pk[js][1] = (unsigned int)f2bf(sv[js][2]) | ((unsigned int)f2bf(sv[js][3]) << 16);
        }
        // ---- PV: O^T += V^T * P^T over two 32-j chunks ----
        int srcA = ((lq & 1) * 2) * 16 + lm;    // source lane for jj 0..3
        int srcB = srcA + 16;                   // source lane for jj 4..7
        bool hi = (lq >> 1);                    // which subtile of the chunk this quad needs
#pragma unroll
        for (int c = 0; c < 2; c++) {
            int a0 = __shfl((int)pk[2 * c][0], srcA);
            int a1 = __shfl((int)pk[2 * c][1], srcA);
            int a2 = __shfl((int)pk[2 * c][0], srcB);
            int a3 = __shfl((int)pk[2 * c][1], srcB);
            int b0 = __shfl((int)pk[2 * c + 1][0], srcA);
            int b1 = __shfl((int)pk[2 * c + 1][1], srcA);
            int b2 = __shfl((int)pk[2 * c + 1][0], srcB);
            int b3 = __shfl((int)pk[2 * c + 1][1], srcB);
            union { int i[4]; short8 s; } pf;
            pf.i[0] = hi ? b0 : a0;
            pf.i[1] = hi ? b1 : a1;
            pf.i[2] = hi ? b2 : a2;
            pf.i[3] = hi ? b3 : a3;
#pragma unroll
            for (int dt = 0; dt < 4; dt++) {
                short8 vf = *(const short8*)&vth[(size_t)(dt * 16 + lm) * T_ + j0 + c * 32 + lq * 8];
                Oacc[dt] = __builtin_amdgcn_mfma_f32_16x16x32_bf16(vf, pf.s, Oacc[dt], 0, 0, 0);
            }
        }
    }
    // ---- epilogue: lane (lm,lq) holds O[irow][dt*16 + lq*4 + r] ----
    float inv = 1.0f / l_i;
    unsigned short* orow = obf + (size_t)(b * T_ + irow) * C_ + h * 64;
#pragma unroll
    for (int dt = 0; dt < 4; dt++) {
        union { unsigned short u[4]; short4v s; } o;
#pragma unroll
        for (int r = 0; r < 4; r++) o.u[r] = f2bf(Oacc[dt][r] * inv);
        *(short4v*)&orow[dt * 16 + lq * 4] = o.s;
    }
}

extern "C" void kernel_launch(void* const* d_in, const int* in_sizes, int n_in,
                              void* d_out, int out_size, void* d_ws, size_t ws_size,
                              hipStream_t stream) {
    const float* x       = (const float*)d_in[0];
    const float* W_attn  = (const float*)d_in[1];
    const float* W_proj  = (const float*)d_in[2];
    const float* W_recip = (const float*)d_in[3];
    const float* w_std   = (const float*)d_in[4];
    const float* w_rec   = (const float*)d_in[5];
    const float* w_disc  = (const float*)d_in[6];
    const float* d_bias  = (const float*)d_in[7];

    char* ws = (char*)d_ws;
    size_t o = 0;
    unsigned short* x_bf = (unsigned short*)(ws + o); o += (size_t)4096 * 1024 * 2;
    unsigned short* wa_t = (unsigned short*)(ws + o); o += (size_t)3072 * 1024 * 2;
    unsigned short* wp_t = (unsigned short*)(ws + o); o += (size_t)1024 * 1024 * 2;
    unsigned short* qkv  = (unsigned short*)(ws + o); o += (size_t)4096 * 3072 * 2;
    unsigned short* qe   = (unsigned short*)(ws + o); o += (size_t)32 * 2048 * 64 * 2;
    unsigned short* ke   = (unsigned short*)(ws + o); o += (size_t)32 * 2048 * 64 * 2;
    unsigned short* vt   = (unsigned short*)(ws + o); o += (size_t)32 * 2048 * 64 * 2;
    unsigned short* obf  = (unsigned short*)(ws + o); o += (size_t)4096 * 1024 * 2;
    float* bias          = (float*)(ws + o);          o += (size_t)16 * 2048 * 4;

    k_cvt<<<2048, 256, 0, stream>>>(x, x_bf, 524288);
    k_tr<<<dim3(48, 16), 256, 0, stream>>>(W_attn, wa_t, 1024, 3072);
    k_tr<<<dim3(16, 16), 256, 0, stream>>>(W_proj, wp_t, 1024, 1024);
    k_bias<<<16, 256, 0, stream>>>(d_bias, w_disc, bias);
    k_gemm<unsigned short><<<dim3(24, 32), 256, 0, stream>>>(x_bf, wa_t, qkv, 4096, 3072, 1024);
    k_build<<<256, 256, 0, stream>>>(qkv, W_recip, w_std, w_rec, qe, ke);
    k_vtr<<<2048, 256, 0, stream>>>(qkv, vt);
    k_attn<<<dim3(32, 32), 256, 0, stream>>>(qe, ke, vt, bias, obf);
    k_gemm<float><<<dim3(8, 32), 256, 0, stream>>>(obf, wp_t, (float*)d_out, 4096, 1024, 1024);
}

// Round 3
// 229.733 us; speedup vs baseline: 1.8307x; 1.8307x over previous
//
#include <hip/hip_runtime.h>
#include <hip/hip_bf16.h>

#define DEVI __device__ __forceinline__

typedef __attribute__((ext_vector_type(8))) short short8;
typedef __attribute__((ext_vector_type(4))) short short4v;
typedef __attribute__((ext_vector_type(4))) float floatx4;

static constexpr int B_ = 2, T_ = 2048, C_ = 1024, H_ = 16, D_ = 64;
static constexpr float LOG2E = 1.44269504088896f;

DEVI float bf2f(unsigned short u) {
    union { unsigned int i; float f; } v; v.i = ((unsigned int)u) << 16; return v.f;
}
DEVI unsigned short f2bf(float f) {
    union { float f; unsigned int i; } v; v.f = f;
    unsigned int x = v.i;
    return (unsigned short)((x + 0x7fffu + ((x >> 16) & 1u)) >> 16);
}
DEVI float fast_exp2(float x) {
#if __has_builtin(__builtin_amdgcn_exp2f)
    return __builtin_amdgcn_exp2f(x);
#else
    return __expf(x * 0.6931471805599453f);
#endif
}

// async global->LDS, 16B per lane. LDS dest must be wave_base + lane*16.
DEVI void async16(const unsigned short* g, unsigned short* l) {
    __builtin_amdgcn_global_load_lds((const __attribute__((address_space(1))) void*)g,
                                     (__attribute__((address_space(3))) void*)l, 16, 0, 0);
}

// ---------------- convert fp32 -> bf16, 8 elems/thread ----------------
__global__ __launch_bounds__(256) void k_cvt(const float* __restrict__ in,
                                             unsigned short* __restrict__ out, int n8) {
    int i = blockIdx.x * 256 + threadIdx.x;
    if (i >= n8) return;
    const float4* p = (const float4*)in + (size_t)i * 2;
    float4 a = p[0], b = p[1];
    union { unsigned short u[8]; short8 s; } r;
    r.u[0] = f2bf(a.x); r.u[1] = f2bf(a.y); r.u[2] = f2bf(a.z); r.u[3] = f2bf(a.w);
    r.u[4] = f2bf(b.x); r.u[5] = f2bf(b.y); r.u[6] = f2bf(b.z); r.u[7] = f2bf(b.w);
    *(short8*)&out[(size_t)i * 8] = r.s;
}

// ---------------- transpose+convert: in f32 (K x N) -> out bf16 (N x K) ----------------
__global__ __launch_bounds__(256) void k_tr(const float* __restrict__ in,
                                            unsigned short* __restrict__ out, int K, int N) {
    __shared__ float tile[64][65];
    int k0 = blockIdx.y * 64, n0 = blockIdx.x * 64;
    int tid = threadIdx.x;
#pragma unroll
    for (int r = 0; r < 4; r++) {
        int ci = tid + r * 256;
        int row = ci >> 4, c4 = (ci & 15) * 4;
        float4 v = *(const float4*)&in[(size_t)(k0 + row) * N + n0 + c4];
        tile[row][c4 + 0] = v.x; tile[row][c4 + 1] = v.y;
        tile[row][c4 + 2] = v.z; tile[row][c4 + 3] = v.w;
    }
    __syncthreads();
#pragma unroll
    for (int r = 0; r < 2; r++) {
        int ci = tid + r * 256;
        int row = ci >> 3, c8 = (ci & 7) * 8;
        union { unsigned short u[8]; short8 s; } o;
#pragma unroll
        for (int j = 0; j < 8; j++) o.u[j] = f2bf(tile[c8 + j][row]);
        *(short8*)&out[(size_t)(n0 + row) * K + k0 + c8] = o.s;
    }
}

// ---------------- discourse bias: (d_bias - mean) * w_disc * log2(e) ----------------
__global__ __launch_bounds__(256) void k_bias(const float* __restrict__ d_bias,
                                              const float* __restrict__ w_disc,
                                              float* __restrict__ bias) {
    int h = blockIdx.x, tid = threadIdx.x;
    __shared__ float red[256];
    float s = 0.f;
    for (int t = tid; t < T_; t += 256) s += d_bias[h * T_ + t];
    red[tid] = s;
    __syncthreads();
    for (int st = 128; st > 0; st >>= 1) {
        if (tid < st) red[tid] += red[tid + st];
        __syncthreads();
    }
    float mean = red[0] * (1.0f / T_);
    float wd = w_disc[h] * LOG2E;
    for (int t = tid; t < T_; t += 256) bias[h * T_ + t] = (d_bias[h * T_ + t] - mean) * wd;
}

// ---------------- bf16 GEMM: C(MxN) = A(MxK) * Bt(NxK)^T ----------------
template <typename OUT>
__global__ __launch_bounds__(256) void k_gemm(const unsigned short* __restrict__ A,
                                              const unsigned short* __restrict__ Bt,
                                              OUT* __restrict__ C, int M, int N, int K) {
    __shared__ __align__(16) unsigned short As[128 * 32];
    __shared__ __align__(16) unsigned short Bs[128 * 32];
    int m0 = blockIdx.y * 128, n0 = blockIdx.x * 128;
    int tid = threadIdx.x, l = tid & 63, w = tid >> 6;
    int wm = (w >> 1) * 64, wn = (w & 1) * 64;
    int lm = l & 15, lq = l >> 4;
    floatx4 acc[4][4];
#pragma unroll
    for (int a = 0; a < 4; a++)
#pragma unroll
        for (int b = 0; b < 4; b++) acc[a][b] = {0.f, 0.f, 0.f, 0.f};

    for (int k0 = 0; k0 < K; k0 += 32) {
        __syncthreads();
#pragma unroll
        for (int r = 0; r < 2; r++) {
            int ci = tid + r * 256;
            int row = ci >> 2, off = (ci & 3) * 8;
            async16(&A[(size_t)(m0 + row) * K + k0 + off], &As[row * 32 + off]);
            async16(&Bt[(size_t)(n0 + row) * K + k0 + off], &Bs[row * 32 + off]);
        }
        __syncthreads();
        short8 af[4], bf[4];
#pragma unroll
        for (int t = 0; t < 4; t++) af[t] = *(short8*)&As[(wm + t * 16 + lm) * 32 + lq * 8];
#pragma unroll
        for (int t = 0; t < 4; t++) bf[t] = *(short8*)&Bs[(wn + t * 16 + lm) * 32 + lq * 8];
#pragma unroll
        for (int tm = 0; tm < 4; tm++)
#pragma unroll
            for (int tn = 0; tn < 4; tn++)
                acc[tm][tn] = __builtin_amdgcn_mfma_f32_16x16x32_bf16(af[tm], bf[tn], acc[tm][tn], 0, 0, 0);
    }
#pragma unroll
    for (int tm = 0; tm < 4; tm++)
#pragma unroll
        for (int tn = 0; tn < 4; tn++) {
            int row = m0 + wm + tm * 16 + lq * 4;
            int col = n0 + wn + tn * 16 + lm;
#pragma unroll
            for (int r = 0; r < 4; r++) {
                float v = acc[tm][tn][r];
                if constexpr (sizeof(OUT) == 2) C[(size_t)(row + r) * N + col] = (OUT)f2bf(v);
                else                            C[(size_t)(row + r) * N + col] = v;
            }
        }
}

// ---------------- build q_eff/k_eff in MFMA-fragment-linear layout ----------------
// layout (shorts): bh*131072 + tile(t>>4)*1024 + half*512 + lq*128 + (t&15)*8 + e
// q_eff folded scale: 0.125 * log2(e)  (softmax scale + log2 domain)
__global__ __launch_bounds__(256) void k_build(const unsigned short* __restrict__ qkv,
                                               const float* __restrict__ W_recip,
                                               const float* __restrict__ w_std,
                                               const float* __restrict__ w_rec,
                                               unsigned short* __restrict__ qe,
                                               unsigned short* __restrict__ ke) {
    __shared__ float Wr[64 * 8];
    int tid = threadIdx.x;
    for (int i = tid; i < 512; i += 256) Wr[i] = W_recip[i];
    __syncthreads();
    int g = blockIdx.x * 256 + tid;       // over B*H*T
    int t = g & (T_ - 1), h = (g >> 11) & (H_ - 1), b = g >> 15;
    float ws = sqrtf(fmaxf(w_std[h], 1e-8f));
    float wr = sqrtf(fmaxf(w_rec[h], 1e-8f));
    bool ra = w_rec[h] > 0.1f;
    const unsigned short* qrow = qkv + (size_t)(b * T_ + t) * 3072 + h * 64;
    const unsigned short* krow = qrow + 1024;
    float q[64], k[64];
#pragma unroll
    for (int i = 0; i < 8; i++) {
        short8 qv = *(const short8*)&qrow[i * 8];
        short8 kv = *(const short8*)&krow[i * 8];
#pragma unroll
        for (int j = 0; j < 8; j++) {
            q[i * 8 + j] = bf2f((unsigned short)qv[j]);
            k[i * 8 + j] = bf2f((unsigned short)kv[j]);
        }
    }
    float QW[8], KW[8];
#pragma unroll
    for (int r = 0; r < 8; r++) { QW[r] = 0.f; KW[r] = 0.f; }
#pragma unroll
    for (int d = 0; d < 64; d++)
#pragma unroll
        for (int r = 0; r < 8; r++) {
            QW[r] += q[d] * Wr[d * 8 + r];
            KW[r] += k[d] * Wr[d * 8 + r];
        }
    const float qscale = 0.125f * LOG2E;
    size_t tbase = (size_t)(b * H_ + h) * 131072 + (size_t)(t >> 4) * 1024 + (size_t)(t & 15) * 8;
#pragma unroll
    for (int i = 0; i < 8; i++) {
        union { unsigned short u[8]; short8 s; } uq, uk;
#pragma unroll
        for (int j = 0; j < 8; j++) {
            int d = i * 8 + j;
            float qv, kv;
            if (ra && d >= 56) { qv = wr * KW[d - 56]; kv = wr * QW[d - 56]; }  // q_aug<-KW, k_aug<-QW
            else               { qv = ws * q[d];       kv = ws * k[d]; }
            uq.u[j] = f2bf(qv * qscale);
            uk.u[j] = f2bf(kv);
        }
        size_t off = tbase + (size_t)(i >> 2) * 512 + (size_t)(i & 3) * 128;
        *(short8*)&qe[off] = uq.s;
        *(short8*)&ke[off] = uk.s;
    }
}

// ---------------- V^T in fragment-linear layout ----------------
// layout (shorts): bh*131072 + j32*2048 + dt*512 + lq*128 + lm*8 + e
//   = V[t = j32*32 + lq*8 + e][d = dt*16 + lm]
__global__ __launch_bounds__(256) void k_vtr(const unsigned short* __restrict__ qkv,
                                             unsigned short* __restrict__ vt) {
    int tid = threadIdx.x;
    int g = blockIdx.x;                    // B*H*(T/32)
    int tchunk = g & 63;
    int h = (g >> 6) & 15, b = g >> 10;
    int d = tid & 63, tg = tid >> 6;
    int t0 = tchunk * 32 + tg * 8;
    union { unsigned short u[8]; short8 s; } v;
#pragma unroll
    for (int i = 0; i < 8; i++)
        v.u[i] = qkv[(size_t)(b * T_ + t0 + i) * 3072 + 2048 + h * 64 + d];
    size_t off = (size_t)((b * H_ + h)) * 131072 + (size_t)tchunk * 2048 +
                 (size_t)(d >> 4) * 512 + (size_t)tg * 128 + (size_t)(d & 15) * 8;
    *(short8*)&vt[off] = v.s;
}

// ---------------- attention helpers ----------------
DEVI void online_softmax(float sv[4][4], float& m_i, float& l_i, floatx4* O,
                         unsigned int pk[4][2]) {
    float mx = sv[0][0];
#pragma unroll
    for (int js = 0; js < 4; js++)
#pragma unroll
        for (int r = 0; r < 4; r++) mx = fmaxf(mx, sv[js][r]);
    mx = fmaxf(mx, __shfl_xor(mx, 16));
    mx = fmaxf(mx, __shfl_xor(mx, 32));
    float mn = fmaxf(m_i, mx);
    float alpha = fast_exp2(m_i - mn);
    m_i = mn;
    float rs = 0.f;
#pragma unroll
    for (int js = 0; js < 4; js++)
#pragma unroll
        for (int r = 0; r < 4; r++) {
            float p = fast_exp2(sv[js][r] - mn);
            sv[js][r] = p;
            rs += p;
        }
    rs += __shfl_xor(rs, 16);
    rs += __shfl_xor(rs, 32);
    l_i = l_i * alpha + rs;
#pragma unroll
    for (int dt = 0; dt < 4; dt++) {
        floatx4 o = O[dt];
        o[0] *= alpha; o[1] *= alpha; o[2] *= alpha; o[3] *= alpha;
        O[dt] = o;
    }
#pragma unroll
    for (int js = 0; js < 4; js++) {
        pk[js][0] = (unsigned int)f2bf(sv[js][0]) | ((unsigned int)f2bf(sv[js][1]) << 16);
        pk[js][1] = (unsigned int)f2bf(sv[js][2]) | ((unsigned int)f2bf(sv[js][3]) << 16);
    }
}

DEVI short8 make_pf(const unsigned int pk[4][2], int c, int srcLo, int srcHi, bool hi) {
    int a0 = __shfl((int)pk[2 * c][0], srcLo);
    int a1 = __shfl((int)pk[2 * c][1], srcLo);
    int a2 = __shfl((int)pk[2 * c][0], srcHi);
    int a3 = __shfl((int)pk[2 * c][1], srcHi);
    int b0 = __shfl((int)pk[2 * c + 1][0], srcLo);
    int b1 = __shfl((int)pk[2 * c + 1][1], srcLo);
    int b2 = __shfl((int)pk[2 * c + 1][0], srcHi);
    int b3 = __shfl((int)pk[2 * c + 1][1], srcHi);
    union { int i[4]; short8 s; } pf;
    pf.i[0] = hi ? b0 : a0;
    pf.i[1] = hi ? b1 : a1;
    pf.i[2] = hi ? b2 : a2;
    pf.i[3] = hi ? b3 : a3;
    return pf.s;
}

// ---------------- flash attention: wave-autonomous, paired tiles, 2-stream ILP ----------------
// Wave owns 16-row q-tiles gA = bx*4+w and gB = 127-gA -> uniform 33 j-tile visits.
// All q/k/v loads are contiguous 1KB wave bursts (fragment-linear layouts).
__global__ __launch_bounds__(256) void k_attn(const unsigned short* __restrict__ qe,
                                              const unsigned short* __restrict__ ke,
                                              const unsigned short* __restrict__ vt,
                                              const float* __restrict__ bias,
                                              unsigned short* __restrict__ obf) {
    int bh = blockIdx.y;
    int b = bh >> 4, h = bh & 15;
    int tid = threadIdx.x, l = tid & 63, w = tid >> 6;
    int lm = l & 15, lq = l >> 4;
    int l8 = l * 8;
    const size_t hb = (size_t)bh * 131072;
    const unsigned short* qeh = qe + hb;
    const unsigned short* keh = ke + hb;
    const unsigned short* vth = vt + hb;
    const float* biash = bias + h * T_;

    int gA = blockIdx.x * 4 + w;
    int gB = 127 - gA;
    int itA = (gA >> 2) + 1, itB = (gB >> 2) + 1;
    int irowA = gA * 16 + lm, irowB = gB * 16 + lm;

    short8 qA0 = *(const short8*)(qeh + (size_t)gA * 1024 + l8);
    short8 qA1 = *(const short8*)(qeh + (size_t)gA * 1024 + 512 + l8);
    short8 qB0 = *(const short8*)(qeh + (size_t)gB * 1024 + l8);
    short8 qB1 = *(const short8*)(qeh + (size_t)gB * 1024 + 512 + l8);

    floatx4 OA[4], OB[4];
#pragma unroll
    for (int i = 0; i < 4; i++) { OA[i] = {0.f, 0.f, 0.f, 0.f}; OB[i] = {0.f, 0.f, 0.f, 0.f}; }
    float mA = -3e38f, lA = 0.f, mB = -3e38f, lB = 0.f;

    const int srcLo = ((lq & 1) * 2) * 16 + lm;
    const int srcHi = srcLo + 16;
    const bool hi = (lq >> 1) & 1;

    int j0 = 0;
    // ---- interleaved phase: both streams share the K/V tile (B never masked here) ----
    for (int s = 0; s < itA; s++, j0 += 64) {
        float svA[4][4], svB[4][4];
#pragma unroll
        for (int js = 0; js < 4; js++) {
            const unsigned short* kp = keh + (size_t)((j0 >> 4) + js) * 1024 + l8;
            short8 kf0 = *(const short8*)kp;
            short8 kf1 = *(const short8*)(kp + 512);
            floatx4 sa = {0.f, 0.f, 0.f, 0.f}, sb = {0.f, 0.f, 0.f, 0.f};
            sa = __builtin_amdgcn_mfma_f32_16x16x32_bf16(kf0, qA0, sa, 0, 0, 0);
            sa = __builtin_amdgcn_mfma_f32_16x16x32_bf16(kf1, qA1, sa, 0, 0, 0);
            sb = __builtin_amdgcn_mfma_f32_16x16x32_bf16(kf0, qB0, sb, 0, 0, 0);
            sb = __builtin_amdgcn_mfma_f32_16x16x32_bf16(kf1, qB1, sb, 0, 0, 0);
            int jb = j0 + js * 16 + lq * 4;
            float4 bj = *(const float4*)&biash[jb];
            float bv[4] = {bj.x, bj.y, bj.z, bj.w};
#pragma unroll
            for (int r = 0; r < 4; r++) {
                svA[js][r] = (jb + r <= irowA) ? (sa[r] + bv[r]) : -1e9f;
                svB[js][r] = sb[r] + bv[r];
            }
        }
        unsigned int pkA[4][2], pkB[4][2];
        online_softmax(svA, mA, lA, OA, pkA);
        online_softmax(svB, mB, lB, OB, pkB);
#pragma unroll
        for (int c = 0; c < 2; c++) {
            short8 pfA = make_pf(pkA, c, srcLo, srcHi, hi);
            short8 pfB = make_pf(pkB, c, srcLo, srcHi, hi);
#pragma unroll
            for (int dt = 0; dt < 4; dt++) {
                short8 vf = *(const short8*)(vth + (size_t)((j0 >> 5) + c) * 2048 + dt * 512 + l8);
                OA[dt] = __builtin_amdgcn_mfma_f32_16x16x32_bf16(vf, pfA, OA[dt], 0, 0, 0);
                OB[dt] = __builtin_amdgcn_mfma_f32_16x16x32_bf16(vf, pfB, OB[dt], 0, 0, 0);
            }
        }
    }
    // ---- tail phase: stream B only ----
    for (int s = itA; s < itB; s++, j0 += 64) {
        float svB[4][4];
#pragma unroll
        for (int js = 0; js < 4; js++) {
            const unsigned short* kp = keh + (size_t)((j0 >> 4) + js) * 1024 + l8;
            short8 kf0 = *(const short8*)kp;
            short8 kf1 = *(const short8*)(kp + 512);
            floatx4 sb = {0.f, 0.f, 0.f, 0.f};
            sb = __builtin_amdgcn_mfma_f32_16x16x32_bf16(kf0, qB0, sb, 0, 0, 0);
            sb = __builtin_amdgcn_mfma_f32_16x16x32_bf16(kf1, qB1, sb, 0, 0, 0);
            int jb = j0 + js * 16 + lq * 4;
            float4 bj = *(const float4*)&biash[jb];
            float bv[4] = {bj.x, bj.y, bj.z, bj.w};
#pragma unroll
            for (int r = 0; r < 4; r++)
                svB[js][r] = (jb + r <= irowB) ? (sb[r] + bv[r]) : -1e9f;
        }
        unsigned int pkB[4][2];
        online_softmax(svB, mB, lB, OB, pkB);
#pragma unroll
        for (int c = 0; c < 2; c++) {
            short8 pfB = make_pf(pkB, c, srcLo, srcHi, hi);
#pragma unroll
            for (int dt = 0; dt < 4; dt++) {
                short8 vf = *(const short8*)(vth + (size_t)((j0 >> 5) + c) * 2048 + dt * 512 + l8);
                OB[dt] = __builtin_amdgcn_mfma_f32_16x16x32_bf16(vf, pfB, OB[dt], 0, 0, 0);
            }
        }
    }
    // ---- epilogue ----
    {
        float inv = 1.0f / lA;
        unsigned short* orow = obf + (size_t)(b * T_ + irowA) * C_ + h * 64;
#pragma unroll
        for (int dt = 0; dt < 4; dt++) {
            union { unsigned short u[4]; short4v s; } o;
#pragma unroll
            for (int r = 0; r < 4; r++) o.u[r] = f2bf(OA[dt][r] * inv);
            *(short4v*)&orow[dt * 16 + lq * 4] = o.s;
        }
    }
    {
        float inv = 1.0f / lB;
        unsigned short* orow = obf + (size_t)(b * T_ + irowB) * C_ + h * 64;
#pragma unroll
        for (int dt = 0; dt < 4; dt++) {
            union { unsigned short u[4]; short4v s; } o;
#pragma unroll
            for (int r = 0; r < 4; r++) o.u[r] = f2bf(OB[dt][r] * inv);
            *(short4v*)&orow[dt * 16 + lq * 4] = o.s;
        }
    }
}

extern "C" void kernel_launch(void* const* d_in, const int* in_sizes, int n_in,
                              void* d_out, int out_size, void* d_ws, size_t ws_size,
                              hipStream_t stream) {
    const float* x       = (const float*)d_in[0];
    const float* W_attn  = (const float*)d_in[1];
    const float* W_proj  = (const float*)d_in[2];
    const float* W_recip = (const float*)d_in[3];
    const float* w_std   = (const float*)d_in[4];
    const float* w_rec   = (const float*)d_in[5];
    const float* w_disc  = (const float*)d_in[6];
    const float* d_bias  = (const float*)d_in[7];

    char* ws = (char*)d_ws;
    size_t o = 0;
    unsigned short* x_bf = (unsigned short*)(ws + o); o += (size_t)4096 * 1024 * 2;
    unsigned short* wa_t = (unsigned short*)(ws + o); o += (size_t)3072 * 1024 * 2;
    unsigned short* wp_t = (unsigned short*)(ws + o); o += (size_t)1024 * 1024 * 2;
    unsigned short* qkv  = (unsigned short*)(ws + o); o += (size_t)4096 * 3072 * 2;
    unsigned short* qe   = (unsigned short*)(ws + o); o += (size_t)32 * 2048 * 64 * 2;
    unsigned short* ke   = (unsigned short*)(ws + o); o += (size_t)32 * 2048 * 64 * 2;
    unsigned short* vt   = (unsigned short*)(ws + o); o += (size_t)32 * 2048 * 64 * 2;
    unsigned short* obf  = (unsigned short*)(ws + o); o += (size_t)4096 * 1024 * 2;
    float* bias          = (float*)(ws + o);          o += (size_t)16 * 2048 * 4;

    k_cvt<<<2048, 256, 0, stream>>>(x, x_bf, 524288);
    k_tr<<<dim3(48, 16), 256, 0, stream>>>(W_attn, wa_t, 1024, 3072);
    k_tr<<<dim3(16, 16), 256, 0, stream>>>(W_proj, wp_t, 1024, 1024);
    k_bias<<<16, 256, 0, stream>>>(d_bias, w_disc, bias);
    k_gemm<unsigned short><<<dim3(24, 32), 256, 0, stream>>>(x_bf, wa_t, qkv, 4096, 3072, 1024);
    k_build<<<256, 256, 0, stream>>>(qkv, W_recip, w_std, w_rec, qe, ke);
    k_vtr<<<2048, 256, 0, stream>>>(qkv, vt);
    k_attn<<<dim3(16, 32), 256, 0, stream>>>(qe, ke, vt, bias, obf);
    k_gemm<float><<<dim3(8, 32), 256, 0, stream>>>(obf, wp_t, (float*)d_out, 4096, 1024, 1024);
}

// Round 4
// 209.738 us; speedup vs baseline: 2.0053x; 1.0953x over previous
//
#include <hip/hip_runtime.h>
#include <hip/hip_bf16.h>

#define DEVI __device__ __forceinline__

typedef __attribute__((ext_vector_type(8))) short short8;
typedef __attribute__((ext_vector_type(4))) short short4v;
typedef __attribute__((ext_vector_type(4))) float floatx4;

static constexpr int B_ = 2, T_ = 2048, C_ = 1024, H_ = 16, D_ = 64;
static constexpr float LOG2E = 1.44269504088896f;

DEVI float bf2f(unsigned short u) {
    union { unsigned int i; float f; } v; v.i = ((unsigned int)u) << 16; return v.f;
}
DEVI unsigned short f2bf(float f) {
    union { float f; unsigned int i; } v; v.f = f;
    unsigned int x = v.i;
    return (unsigned short)((x + 0x7fffu + ((x >> 16) & 1u)) >> 16);
}
DEVI unsigned int pk2bf(float lo, float hi) {
#if __has_builtin(__builtin_amdgcn_cvt_pk_bf16_f32)
    typedef __attribute__((ext_vector_type(2))) __bf16 bf16x2;
    union { bf16x2 v; unsigned int u; } r;
    r.v = __builtin_amdgcn_cvt_pk_bf16_f32(lo, hi);
    return r.u;
#else
    return (unsigned int)f2bf(lo) | ((unsigned int)f2bf(hi) << 16);
#endif
}
DEVI float fast_exp2(float x) {
#if __has_builtin(__builtin_amdgcn_exp2f)
    return __builtin_amdgcn_exp2f(x);
#else
    return __expf(x * 0.6931471805599453f);
#endif
}

// async global->LDS, 16B per lane. LDS dest must be wave_base + lane*16.
DEVI void async16(const unsigned short* g, unsigned short* l) {
    __builtin_amdgcn_global_load_lds((const __attribute__((address_space(1))) void*)g,
                                     (__attribute__((address_space(3))) void*)l, 16, 0, 0);
}

// ================= fused prep: x->bf16, W_attn^T, W_proj^T, bias =================
DEVI void tr_body(const float* in, unsigned short* out, int K, int N, int bx, int by,
                  int tid, float (*tile)[65]) {
    int k0 = by * 64, n0 = bx * 64;
#pragma unroll
    for (int r = 0; r < 4; r++) {
        int ci = tid + r * 256;
        int row = ci >> 4, c4 = (ci & 15) * 4;
        float4 v = *(const float4*)&in[(size_t)(k0 + row) * N + n0 + c4];
        tile[row][c4 + 0] = v.x; tile[row][c4 + 1] = v.y;
        tile[row][c4 + 2] = v.z; tile[row][c4 + 3] = v.w;
    }
    __syncthreads();
#pragma unroll
    for (int r = 0; r < 2; r++) {
        int ci = tid + r * 256;
        int row = ci >> 3, c8 = (ci & 7) * 8;
        union { unsigned short u[8]; short8 s; } o;
#pragma unroll
        for (int j = 0; j < 8; j++) o.u[j] = f2bf(tile[c8 + j][row]);
        *(short8*)&out[(size_t)(n0 + row) * K + k0 + c8] = o.s;
    }
}

__global__ __launch_bounds__(256) void k_prep(const float* __restrict__ x,
                                              const float* __restrict__ W_attn,
                                              const float* __restrict__ W_proj,
                                              const float* __restrict__ d_bias,
                                              const float* __restrict__ w_disc,
                                              unsigned short* __restrict__ x_bf,
                                              unsigned short* __restrict__ wa_t,
                                              unsigned short* __restrict__ wp_t,
                                              float* __restrict__ bias) {
    __shared__ float tile[64][65];
    __shared__ float red[256];
    int bid = blockIdx.x, tid = threadIdx.x;
    if (bid < 2048) {
        int i = bid * 256 + tid;
        const float4* p = (const float4*)x + (size_t)i * 2;
        float4 a = p[0], b = p[1];
        union { unsigned short u[8]; short8 s; } r;
        r.u[0] = f2bf(a.x); r.u[1] = f2bf(a.y); r.u[2] = f2bf(a.z); r.u[3] = f2bf(a.w);
        r.u[4] = f2bf(b.x); r.u[5] = f2bf(b.y); r.u[6] = f2bf(b.z); r.u[7] = f2bf(b.w);
        *(short8*)&x_bf[(size_t)i * 8] = r.s;
    } else if (bid < 2816) {
        int idx = bid - 2048;
        tr_body(W_attn, wa_t, 1024, 3072, idx % 48, idx / 48, tid, tile);
    } else if (bid < 3072) {
        int idx = bid - 2816;
        tr_body(W_proj, wp_t, 1024, 1024, idx & 15, idx >> 4, tid, tile);
    } else {
        int h = bid - 3072;
        float s = 0.f;
        for (int t = tid; t < T_; t += 256) s += d_bias[h * T_ + t];
        red[tid] = s;
        __syncthreads();
        for (int st = 128; st > 0; st >>= 1) {
            if (tid < st) red[tid] += red[tid + st];
            __syncthreads();
        }
        float mean = red[0] * (1.0f / T_);
        float wd = w_disc[h] * LOG2E;
        for (int t = tid; t < T_; t += 256) bias[h * T_ + t] = (d_bias[h * T_ + t] - mean) * wd;
    }
}

// ================= bf16 GEMM 128x128: C = A(MxK) * Bt(NxK)^T =================
template <typename OUT>
__global__ __launch_bounds__(256) void k_gemm(const unsigned short* __restrict__ A,
                                              const unsigned short* __restrict__ Bt,
                                              OUT* __restrict__ C, int M, int N, int K) {
    __shared__ __align__(16) unsigned short As[128 * 32];
    __shared__ __align__(16) unsigned short Bs[128 * 32];
    int m0 = blockIdx.y * 128, n0 = blockIdx.x * 128;
    int tid = threadIdx.x, l = tid & 63, w = tid >> 6;
    int wm = (w >> 1) * 64, wn = (w & 1) * 64;
    int lm = l & 15, lq = l >> 4;
    floatx4 acc[4][4];
#pragma unroll
    for (int a = 0; a < 4; a++)
#pragma unroll
        for (int b = 0; b < 4; b++) acc[a][b] = {0.f, 0.f, 0.f, 0.f};

    for (int k0 = 0; k0 < K; k0 += 32) {
        __syncthreads();
#pragma unroll
        for (int r = 0; r < 2; r++) {
            int ci = tid + r * 256;
            int row = ci >> 2, off = (ci & 3) * 8;
            async16(&A[(size_t)(m0 + row) * K + k0 + off], &As[row * 32 + off]);
            async16(&Bt[(size_t)(n0 + row) * K + k0 + off], &Bs[row * 32 + off]);
        }
        __syncthreads();
        short8 af[4], bf[4];
#pragma unroll
        for (int t = 0; t < 4; t++) af[t] = *(short8*)&As[(wm + t * 16 + lm) * 32 + lq * 8];
#pragma unroll
        for (int t = 0; t < 4; t++) bf[t] = *(short8*)&Bs[(wn + t * 16 + lm) * 32 + lq * 8];
#pragma unroll
        for (int tm = 0; tm < 4; tm++)
#pragma unroll
            for (int tn = 0; tn < 4; tn++)
                acc[tm][tn] = __builtin_amdgcn_mfma_f32_16x16x32_bf16(af[tm], bf[tn], acc[tm][tn], 0, 0, 0);
    }
#pragma unroll
    for (int tm = 0; tm < 4; tm++)
#pragma unroll
        for (int tn = 0; tn < 4; tn++) {
            int row = m0 + wm + tm * 16 + lq * 4;
            int col = n0 + wn + tn * 16 + lm;
#pragma unroll
            for (int r = 0; r < 4; r++) {
                float v = acc[tm][tn][r];
                if constexpr (sizeof(OUT) == 2) C[(size_t)(row + r) * N + col] = (OUT)f2bf(v);
                else                            C[(size_t)(row + r) * N + col] = v;
            }
        }
}

// ================= bf16 GEMM 128x64 (fp32 out) — for the proj GEMM =================
__global__ __launch_bounds__(256) void k_gemm64(const unsigned short* __restrict__ A,
                                                const unsigned short* __restrict__ Bt,
                                                float* __restrict__ C, int M, int N, int K) {
    __shared__ __align__(16) unsigned short As[128 * 32];
    __shared__ __align__(16) unsigned short Bs[64 * 32];
    int m0 = blockIdx.y * 128, n0 = blockIdx.x * 64;
    int tid = threadIdx.x, l = tid & 63, w = tid >> 6;
    int wm = w * 32;
    int lm = l & 15, lq = l >> 4;
    floatx4 acc[2][4];
#pragma unroll
    for (int a = 0; a < 2; a++)
#pragma unroll
        for (int b = 0; b < 4; b++) acc[a][b] = {0.f, 0.f, 0.f, 0.f};

    for (int k0 = 0; k0 < K; k0 += 32) {
        __syncthreads();
#pragma unroll
        for (int r = 0; r < 2; r++) {
            int ci = tid + r * 256;
            int row = ci >> 2, off = (ci & 3) * 8;
            async16(&A[(size_t)(m0 + row) * K + k0 + off], &As[row * 32 + off]);
        }
        {
            int row = tid >> 2, off = (tid & 3) * 8;
            async16(&Bt[(size_t)(n0 + row) * K + k0 + off], &Bs[row * 32 + off]);
        }
        __syncthreads();
        short8 af[2], bf[4];
#pragma unroll
        for (int t = 0; t < 2; t++) af[t] = *(short8*)&As[(wm + t * 16 + lm) * 32 + lq * 8];
#pragma unroll
        for (int t = 0; t < 4; t++) bf[t] = *(short8*)&Bs[(t * 16 + lm) * 32 + lq * 8];
#pragma unroll
        for (int tm = 0; tm < 2; tm++)
#pragma unroll
            for (int tn = 0; tn < 4; tn++)
                acc[tm][tn] = __builtin_amdgcn_mfma_f32_16x16x32_bf16(af[tm], bf[tn], acc[tm][tn], 0, 0, 0);
    }
#pragma unroll
    for (int tm = 0; tm < 2; tm++)
#pragma unroll
        for (int tn = 0; tn < 4; tn++) {
            int row = m0 + wm + tm * 16 + lq * 4;
            int col = n0 + tn * 16 + lm;
#pragma unroll
            for (int r = 0; r < 4; r++) C[(size_t)(row + r) * N + col] = acc[tm][tn][r];
        }
}

// ================= fused build(q_eff,k_eff) + V^T, fragment-linear =================
DEVI void build_body(const unsigned short* qkv, const float* Wr, const float* w_std,
                     const float* w_rec, unsigned short* qe, unsigned short* ke, int g) {
    int t = g & (T_ - 1), h = (g >> 11) & (H_ - 1), b = g >> 15;
    float ws = sqrtf(fmaxf(w_std[h], 1e-8f));
    float wr = sqrtf(fmaxf(w_rec[h], 1e-8f));
    bool ra = w_rec[h] > 0.1f;
    const unsigned short* qrow = qkv + (size_t)(b * T_ + t) * 3072 + h * 64;
    const unsigned short* krow = qrow + 1024;
    float q[64], k[64];
#pragma unroll
    for (int i = 0; i < 8; i++) {
        short8 qv = *(const short8*)&qrow[i * 8];
        short8 kv = *(const short8*)&krow[i * 8];
#pragma unroll
        for (int j = 0; j < 8; j++) {
            q[i * 8 + j] = bf2f((unsigned short)qv[j]);
            k[i * 8 + j] = bf2f((unsigned short)kv[j]);
        }
    }
    float QW[8], KW[8];
#pragma unroll
    for (int r = 0; r < 8; r++) { QW[r] = 0.f; KW[r] = 0.f; }
#pragma unroll
    for (int d = 0; d < 64; d++)
#pragma unroll
        for (int r = 0; r < 8; r++) {
            QW[r] += q[d] * Wr[d * 8 + r];
            KW[r] += k[d] * Wr[d * 8 + r];
        }
    const float qscale = 0.125f * LOG2E;
    size_t tbase = (size_t)(b * H_ + h) * 131072 + (size_t)(t >> 4) * 1024 + (size_t)(t & 15) * 8;
#pragma unroll
    for (int i = 0; i < 8; i++) {
        union { unsigned short u[8]; short8 s; } uq, uk;
#pragma unroll
        for (int j = 0; j < 8; j++) {
            int d = i * 8 + j;
            float qv, kv;
            if (ra && d >= 56) { qv = wr * KW[d - 56]; kv = wr * QW[d - 56]; }  // q_aug<-KW, k_aug<-QW
            else               { qv = ws * q[d];       kv = ws * k[d]; }
            uq.u[j] = f2bf(qv * qscale);
            uk.u[j] = f2bf(kv);
        }
        size_t off = tbase + (size_t)(i >> 2) * 512 + (size_t)(i & 3) * 128;
        *(short8*)&qe[off] = uq.s;
        *(short8*)&ke[off] = uk.s;
    }
}

__global__ __launch_bounds__(256) void k_bv(const unsigned short* __restrict__ qkv,
                                            const float* __restrict__ W_recip,
                                            const float* __restrict__ w_std,
                                            const float* __restrict__ w_rec,
                                            unsigned short* __restrict__ qe,
                                            unsigned short* __restrict__ ke,
                                            unsigned short* __restrict__ vt) {
    __shared__ float Wr[64 * 8];
    int bid = blockIdx.x, tid = threadIdx.x;
    if (bid < 256) {
        for (int i = tid; i < 512; i += 256) Wr[i] = W_recip[i];
        __syncthreads();
        build_body(qkv, Wr, w_std, w_rec, qe, ke, bid * 256 + tid);
    } else {
        int g = bid - 256;                 // B*H*(T/32)
        int tchunk = g & 63;
        int h = (g >> 6) & 15, b = g >> 10;
        int d = tid & 63, tg = tid >> 6;
        int t0 = tchunk * 32 + tg * 8;
        union { unsigned short u[8]; short8 s; } v;
#pragma unroll
        for (int i = 0; i < 8; i++)
            v.u[i] = qkv[(size_t)(b * T_ + t0 + i) * 3072 + 2048 + h * 64 + d];
        size_t off = (size_t)((b * H_ + h)) * 131072 + (size_t)tchunk * 2048 +
                     (size_t)(d >> 4) * 512 + (size_t)tg * 128 + (size_t)(d & 15) * 8;
        *(short8*)&vt[off] = v.s;
    }
}

// ================= attention helpers =================
DEVI void online_softmax(float sv[4][4], float& m_i, float& l_i, floatx4* O,
                         unsigned int pk[4][2]) {
    float mx = sv[0][0];
#pragma unroll
    for (int js = 0; js < 4; js++)
#pragma unroll
        for (int r = 0; r < 4; r++) mx = fmaxf(mx, sv[js][r]);
    mx = fmaxf(mx, __shfl_xor(mx, 16));
    mx = fmaxf(mx, __shfl_xor(mx, 32));
    float mn = fmaxf(m_i, mx);
    float alpha = fast_exp2(m_i - mn);
    m_i = mn;
    float rs = 0.f;
#pragma unroll
    for (int js = 0; js < 4; js++)
#pragma unroll
        for (int r = 0; r < 4; r++) {
            float p = fast_exp2(sv[js][r] - mn);
            sv[js][r] = p;
            rs += p;
        }
    rs += __shfl_xor(rs, 16);
    rs += __shfl_xor(rs, 32);
    l_i = l_i * alpha + rs;
#pragma unroll
    for (int dt = 0; dt < 4; dt++) {
        floatx4 o = O[dt];
        o[0] *= alpha; o[1] *= alpha; o[2] *= alpha; o[3] *= alpha;
        O[dt] = o;
    }
#pragma unroll
    for (int js = 0; js < 4; js++) {
        pk[js][0] = pk2bf(sv[js][0], sv[js][1]);
        pk[js][1] = pk2bf(sv[js][2], sv[js][3]);
    }
}

DEVI short8 make_pf(const unsigned int pk[4][2], int c, int srcLo, int srcHi, bool hi) {
    int a0 = __shfl((int)pk[2 * c][0], srcLo);
    int a1 = __shfl((int)pk[2 * c][1], srcLo);
    int a2 = __shfl((int)pk[2 * c][0], srcHi);
    int a3 = __shfl((int)pk[2 * c][1], srcHi);
    int b0 = __shfl((int)pk[2 * c + 1][0], srcLo);
    int b1 = __shfl((int)pk[2 * c + 1][1], srcLo);
    int b2 = __shfl((int)pk[2 * c + 1][0], srcHi);
    int b3 = __shfl((int)pk[2 * c + 1][1], srcHi);
    union { int i[4]; short8 s; } pf;
    pf.i[0] = hi ? b0 : a0;
    pf.i[1] = hi ? b1 : a1;
    pf.i[2] = hi ? b2 : a2;
    pf.i[3] = hi ? b3 : a3;
    return pf.s;
}

struct KF { short8 lo[4]; short8 hi[4]; };

// ================= flash attention: wave-autonomous, paired, K double-buffered =================
__global__ __launch_bounds__(256, 2) void k_attn(const unsigned short* __restrict__ qe,
                                                 const unsigned short* __restrict__ ke,
                                                 const unsigned short* __restrict__ vt,
                                                 const float* __restrict__ bias,
                                                 unsigned short* __restrict__ obf) {
    int bh = blockIdx.y;
    int b = bh >> 4, h = bh & 15;
    int tid = threadIdx.x, l = tid & 63, w = tid >> 6;
    int lm = l & 15, lq = l >> 4;
    int l8 = l * 8;
    const size_t hb = (size_t)bh * 131072;
    const unsigned short* qeh = qe + hb;
    const unsigned short* keh = ke + hb;
    const unsigned short* vth = vt + hb;
    const float* biash = bias + h * T_;

    int gA = blockIdx.x * 4 + w;            // 0..63 (light tile)
    int gB = 127 - gA;                      // 64..127 (heavy tile)
    int itA = (gA >> 2) + 1, itB = (gB >> 2) + 1;
    int irowA = gA * 16 + lm, irowB = gB * 16 + lm;

    short8 qA0 = *(const short8*)(qeh + (size_t)gA * 1024 + l8);
    short8 qA1 = *(const short8*)(qeh + (size_t)gA * 1024 + 512 + l8);
    short8 qB0 = *(const short8*)(qeh + (size_t)gB * 1024 + l8);
    short8 qB1 = *(const short8*)(qeh + (size_t)gB * 1024 + 512 + l8);

    floatx4 OA[4], OB[4];
#pragma unroll
    for (int i = 0; i < 4; i++) { OA[i] = {0.f, 0.f, 0.f, 0.f}; OB[i] = {0.f, 0.f, 0.f, 0.f}; }
    float mA = -3e38f, lA = 0.f, mB = -3e38f, lB = 0.f;

    const int srcLo = ((lq & 1) * 2) * 16 + lm;
    const int srcHi = srcLo + 16;
    const bool hi = (lq >> 1) & 1;

    KF kfa, kfb;
#pragma unroll
    for (int js = 0; js < 4; js++) {
        const unsigned short* kp = keh + (size_t)js * 1024 + l8;
        kfa.lo[js] = *(const short8*)kp;
        kfa.hi[js] = *(const short8*)(kp + 512);
    }

    auto step = [&](int s, KF& cur, KF& nxt) {
        int j0 = s * 64;
        bool doA = (s < itA);
        bool maskA = (s == itA - 1);
        bool maskB = (s == itB - 1);
        // prefetch next K tile (overread past last tile is harmless: lands in vt)
        {
            const unsigned short* kb = keh + (size_t)(s + 1) * 4096 + l8;
#pragma unroll
            for (int js = 0; js < 4; js++) {
                nxt.lo[js] = *(const short8*)(kb + js * 1024);
                nxt.hi[js] = *(const short8*)(kb + js * 1024 + 512);
            }
        }
        // V fragments for this tile
        short8 vfr[2][4];
#pragma unroll
        for (int c = 0; c < 2; c++)
#pragma unroll
            for (int dt = 0; dt < 4; dt++)
                vfr[c][dt] = *(const short8*)(vth + (size_t)((j0 >> 5) + c) * 2048 + dt * 512 + l8);
        // QK MFMAs first (B always, A if live)
        floatx4 sb4[4], sa4[4];
#pragma unroll
        for (int js = 0; js < 4; js++) {
            floatx4 sb = {0.f, 0.f, 0.f, 0.f};
            sb = __builtin_amdgcn_mfma_f32_16x16x32_bf16(cur.lo[js], qB0, sb, 0, 0, 0);
            sb = __builtin_amdgcn_mfma_f32_16x16x32_bf16(cur.hi[js], qB1, sb, 0, 0, 0);
            sb4[js] = sb;
        }
        if (doA) {
#pragma unroll
            for (int js = 0; js < 4; js++) {
                floatx4 sa = {0.f, 0.f, 0.f, 0.f};
                sa = __builtin_amdgcn_mfma_f32_16x16x32_bf16(cur.lo[js], qA0, sa, 0, 0, 0);
                sa = __builtin_amdgcn_mfma_f32_16x16x32_bf16(cur.hi[js], qA1, sa, 0, 0, 0);
                sa4[js] = sa;
            }
        }
        // bias
        float bv[4][4];
#pragma unroll
        for (int js = 0; js < 4; js++) {
            float4 bj = *(const float4*)&biash[j0 + js * 16 + lq * 4];
            bv[js][0] = bj.x; bv[js][1] = bj.y; bv[js][2] = bj.z; bv[js][3] = bj.w;
        }
        // stream B softmax
        float svB[4][4];
#pragma unroll
        for (int js = 0; js < 4; js++)
#pragma unroll
            for (int r = 0; r < 4; r++) svB[js][r] = sb4[js][r] + bv[js][r];
        if (maskB) {
#pragma unroll
            for (int js = 0; js < 4; js++) {
                int jb = j0 + js * 16 + lq * 4;
#pragma unroll
                for (int r = 0; r < 4; r++)
                    if (jb + r > irowB) svB[js][r] = -1e9f;
            }
        }
        unsigned int pkB[4][2];
        online_softmax(svB, mB, lB, OB, pkB);

        if (doA) {
            float svA[4][4];
#pragma unroll
            for (int js = 0; js < 4; js++)
#pragma unroll
                for (int r = 0; r < 4; r++) svA[js][r] = sa4[js][r] + bv[js][r];
            if (maskA) {
#pragma unroll
                for (int js = 0; js < 4; js++) {
                    int jb = j0 + js * 16 + lq * 4;
#pragma unroll
                    for (int r = 0; r < 4; r++)
                        if (jb + r > irowA) svA[js][r] = -1e9f;
                }
            }
            unsigned int pkA[4][2];
            online_softmax(svA, mA, lA, OA, pkA);
#pragma unroll
            for (int c = 0; c < 2; c++) {
                short8 pfA = make_pf(pkA, c, srcLo, srcHi, hi);
                short8 pfB = make_pf(pkB, c, srcLo, srcHi, hi);
#pragma unroll
                for (int dt = 0; dt < 4; dt++) {
                    OA[dt] = __builtin_amdgcn_mfma_f32_16x16x32_bf16(vfr[c][dt], pfA, OA[dt], 0, 0, 0);
                    OB[dt] = __builtin_amdgcn_mfma_f32_16x16x32_bf16(vfr[c][dt], pfB, OB[dt], 0, 0, 0);
                }
            }
        } else {
#pragma unroll
            for (int c = 0; c < 2; c++) {
                short8 pfB = make_pf(pkB, c, srcLo, srcHi, hi);
#pragma unroll
                for (int dt = 0; dt < 4; dt++)
                    OB[dt] = __builtin_amdgcn_mfma_f32_16x16x32_bf16(vfr[c][dt], pfB, OB[dt], 0, 0, 0);
            }
        }
    };

    int s = 0;
    for (; s + 2 <= itB; s += 2) {       // ping-pong: no register-swap movs
        step(s, kfa, kfb);
        step(s + 1, kfb, kfa);
    }
    if (s < itB) step(s, kfa, kfb);

    // epilogue
    {
        float inv = 1.0f / lA;
        unsigned short* orow = obf + (size_t)(b * T_ + irowA) * C_ + h * 64;
#pragma unroll
        for (int dt = 0; dt < 4; dt++) {
            union { unsigned short u[4]; short4v s4; } o;
#pragma unroll
            for (int r = 0; r < 4; r++) o.u[r] = f2bf(OA[dt][r] * inv);
            *(short4v*)&orow[dt * 16 + lq * 4] = o.s4;
        }
    }
    {
        float inv = 1.0f / lB;
        unsigned short* orow = obf + (size_t)(b * T_ + irowB) * C_ + h * 64;
#pragma unroll
        for (int dt = 0; dt < 4; dt++) {
            union { unsigned short u[4]; short4v s4; } o;
#pragma unroll
            for (int r = 0; r < 4; r++) o.u[r] = f2bf(OB[dt][r] * inv);
            *(short4v*)&orow[dt * 16 + lq * 4] = o.s4;
        }
    }
}

extern "C" void kernel_launch(void* const* d_in, const int* in_sizes, int n_in,
                              void* d_out, int out_size, void* d_ws, size_t ws_size,
                              hipStream_t stream) {
    const float* x       = (const float*)d_in[0];
    const float* W_attn  = (const float*)d_in[1];
    const float* W_proj  = (const float*)d_in[2];
    const float* W_recip = (const float*)d_in[3];
    const float* w_std   = (const float*)d_in[4];
    const float* w_rec   = (const float*)d_in[5];
    const float* w_disc  = (const float*)d_in[6];
    const float* d_bias  = (const float*)d_in[7];

    char* ws = (char*)d_ws;
    size_t o = 0;
    unsigned short* x_bf = (unsigned short*)(ws + o); o += (size_t)4096 * 1024 * 2;
    unsigned short* wa_t = (unsigned short*)(ws + o); o += (size_t)3072 * 1024 * 2;
    unsigned short* wp_t = (unsigned short*)(ws + o); o += (size_t)1024 * 1024 * 2;
    unsigned short* qkv  = (unsigned short*)(ws + o); o += (size_t)4096 * 3072 * 2;
    unsigned short* qe   = (unsigned short*)(ws + o); o += (size_t)32 * 2048 * 64 * 2;
    unsigned short* ke   = (unsigned short*)(ws + o); o += (size_t)32 * 2048 * 64 * 2;  // k_attn may overread ~8KB into vt: harmless
    unsigned short* vt   = (unsigned short*)(ws + o); o += (size_t)32 * 2048 * 64 * 2;
    unsigned short* obf  = (unsigned short*)(ws + o); o += (size_t)4096 * 1024 * 2;
    float* bias          = (float*)(ws + o);          o += (size_t)16 * 2048 * 4;

    k_prep<<<3088, 256, 0, stream>>>(x, W_attn, W_proj, d_bias, w_disc, x_bf, wa_t, wp_t, bias);
    k_gemm<unsigned short><<<dim3(24, 32), 256, 0, stream>>>(x_bf, wa_t, qkv, 4096, 3072, 1024);
    k_bv<<<2304, 256, 0, stream>>>(qkv, W_recip, w_std, w_rec, qe, ke, vt);
    k_attn<<<dim3(16, 32), 256, 0, stream>>>(qe, ke, vt, bias, obf);
    k_gemm64<<<dim3(16, 32), 256, 0, stream>>>(obf, wp_t, (float*)d_out, 4096, 1024, 1024);
}